// Round 4
// baseline (653.206 us; speedup 1.0000x reference)
//
#include <hip/hip_runtime.h>
#include <hip/hip_bf16.h>
#include <math.h>

// Problem constants
#define BATCH 32
#define TLEN  4096
#define DDIM  512
#define BM    64      // rows (b*T+t) per block
#define BLOCK 512     // 8 waves; wave w owns cols [w*64, w*64+64), all BM rows

typedef __attribute__((ext_vector_type(8))) short bf16x8;  // MFMA A/B frag (4 VGPRs)
typedef __attribute__((ext_vector_type(4))) float f32x4;   // MFMA C/D frag
typedef __attribute__((ext_vector_type(4))) short s16x4;   // 8B LDS store

__device__ __forceinline__ short f32_to_bf16_rne(float f) {
    union { float f; unsigned int u; } v; v.f = f;
    unsigned int r = (v.u + 0x7FFFu + ((v.u >> 16) & 1u)) >> 16;
    return (short)r;
}
__device__ __forceinline__ float fast_tanh(float x) {
    x = fminf(fmaxf(x, -15.f), 15.f);
    float t = __expf(2.0f * x);
    return (t - 1.0f) / (t + 1.0f);
}

// XOR swizzle on 16B (8-short) granules. Measured 0 bank conflicts (r2, r3).
__device__ __forceinline__ int lds_idx(int r, int c) {
    int g = (c >> 3) ^ (r & 31);
    return r * DDIM + (g << 3) + (c & 7);
}

// --- kernel 1: W fp32 -> bf16, zero l/g accumulators -------------------------
__global__ void prep_kernel(const float* __restrict__ W1, const float* __restrict__ W2,
                            short* __restrict__ W1b, short* __restrict__ W2b,
                            float* __restrict__ lbuf, float* __restrict__ gbuf) {
    int i = blockIdx.x * blockDim.x + threadIdx.x;   // 0 .. 262143
    W1b[i] = f32_to_bf16_rne(W1[i]);
    W2b[i] = f32_to_bf16_rne(W2[i]);
    if (i < BATCH * DDIM) { lbuf[i] = 0.f; gbuf[i] = 0.f; }
}

// --- kernel 2: fused u=tanh(hW1^T+b1); s=uW2^T; accumulate l,g ---------------
// Single 64 KB LDS buffer (h tile, later overwritten by u tile) -> 2 blocks/CU
// via LDS limit. IMPORTANT: launch_bounds min-waves stays at 2 — round 3 showed
// (512,4) caps arch-VGPRs at 64 and spills to scratch (WRITE_SIZE 8->211 MB,
// dur +30us). At the natural ~120 VGPRs the HW already fits 16 waves/CU.
__global__ __launch_bounds__(BLOCK, 2)
void main_kernel(const float* __restrict__ h,
                 const short* __restrict__ W1b,
                 const float* __restrict__ b1,
                 const short* __restrict__ W2b,
                 float* __restrict__ lbuf, float* __restrict__ gbuf) {
    __shared__ short sh[BM * DDIM];   // 64 KB: h tile, then u tile (swizzled)

    const int tid  = threadIdx.x;
    const int row0 = blockIdx.x * BM;
    const int b    = row0 / TLEN;       // BM divides TLEN: no batch straddle

    // ---- stage 1: global fp32 h -> LDS bf16 (coalesced float4 loads) ----
    {
        const float4* hp = (const float4*)(h + (size_t)row0 * DDIM);
        #pragma unroll
        for (int i = 0; i < (BM * DDIM / 4) / BLOCK; ++i) {   // 16 iters
            int idx  = tid + i * BLOCK;          // float4 index
            float4 v = hp[idx];
            int flat = idx * 4;
            int r = flat >> 9;                   // /512
            int c = flat & (DDIM - 1);
            s16x4 p;
            p.x = f32_to_bf16_rne(v.x); p.y = f32_to_bf16_rne(v.y);
            p.z = f32_to_bf16_rne(v.z); p.w = f32_to_bf16_rne(v.w);
            *(s16x4*)&sh[lds_idx(r, c)] = p;
        }
    }
    __syncthreads();

    const int wave  = tid >> 6;
    const int lane  = tid & 63;
    const int quad  = lane >> 4;
    const int l16   = lane & 15;
    const int wcol0 = wave * 64;        // this wave's 64-col slice
    const int kq    = quad * 8;

    // ================= GEMM1: u = tanh(h @ W1^T + b1) =================
    f32x4 acc[4][4];                    // [rowblk][colblk]
    #pragma unroll
    for (int rb = 0; rb < 4; ++rb)
        #pragma unroll
        for (int cb = 0; cb < 4; ++cb) acc[rb][cb] = (f32x4){0.f, 0.f, 0.f, 0.f};

    {
        const short* Bb = W1b + (size_t)(wcol0 + l16) * DDIM + kq;
        bf16x8 bcur[4], bnxt[4];
        #pragma unroll
        for (int cb = 0; cb < 4; ++cb)
            bcur[cb] = *(const bf16x8*)(Bb + cb * 16 * DDIM);

        for (int k0 = 0; k0 < DDIM; k0 += 32) {
            bf16x8 af[4];
            #pragma unroll
            for (int rb = 0; rb < 4; ++rb)
                af[rb] = *(const bf16x8*)&sh[lds_idx(rb * 16 + l16, k0 + kq)];
            // prefetch next k-chunk of B (last iter overreads into adjacent ws
            // buffers -- allocated, unused)
            #pragma unroll
            for (int cb = 0; cb < 4; ++cb)
                bnxt[cb] = *(const bf16x8*)(Bb + cb * 16 * DDIM + k0 + 32);
            #pragma unroll
            for (int cb = 0; cb < 4; ++cb)
                #pragma unroll
                for (int rb = 0; rb < 4; ++rb)
                    acc[rb][cb] = __builtin_amdgcn_mfma_f32_16x16x32_bf16(
                        af[rb], bcur[cb], acc[rb][cb], 0, 0, 0);
            #pragma unroll
            for (int cb = 0; cb < 4; ++cb) bcur[cb] = bnxt[cb];
        }
    }

    __syncthreads();   // all waves done reading h tile before u overwrites it

    // epilogue 1: u = tanh(acc + bias) -> sh (overwrite h tile)
    #pragma unroll
    for (int cb = 0; cb < 4; ++cb) {
        int col  = wcol0 + cb * 16 + l16;
        float bias = b1[col];
        #pragma unroll
        for (int rb = 0; rb < 4; ++rb)
            #pragma unroll
            for (int r = 0; r < 4; ++r) {
                int row = rb * 16 + quad * 4 + r;   // C/D: col=lane&15, row=quad*4+reg
                sh[lds_idx(row, col)] =
                    f32_to_bf16_rne(fast_tanh(acc[rb][cb][r] + bias));
            }
    }
    __syncthreads();

    // ================= GEMM2: s = u @ W2^T; accumulate l,g =================
    #pragma unroll
    for (int rb = 0; rb < 4; ++rb)
        #pragma unroll
        for (int cb = 0; cb < 4; ++cb) acc[rb][cb] = (f32x4){0.f, 0.f, 0.f, 0.f};

    {
        const short* Bb = W2b + (size_t)(wcol0 + l16) * DDIM + kq;
        bf16x8 bcur[4], bnxt[4];
        #pragma unroll
        for (int cb = 0; cb < 4; ++cb)
            bcur[cb] = *(const bf16x8*)(Bb + cb * 16 * DDIM);

        for (int k0 = 0; k0 < DDIM; k0 += 32) {
            bf16x8 af[4];
            #pragma unroll
            for (int rb = 0; rb < 4; ++rb)
                af[rb] = *(const bf16x8*)&sh[lds_idx(rb * 16 + l16, k0 + kq)];
            #pragma unroll
            for (int cb = 0; cb < 4; ++cb)
                bnxt[cb] = *(const bf16x8*)(Bb + cb * 16 * DDIM + k0 + 32);
            #pragma unroll
            for (int cb = 0; cb < 4; ++cb)
                #pragma unroll
                for (int rb = 0; rb < 4; ++rb)
                    acc[rb][cb] = __builtin_amdgcn_mfma_f32_16x16x32_bf16(
                        af[rb], bcur[cb], acc[rb][cb], 0, 0, 0);
            #pragma unroll
            for (int cb = 0; cb < 4; ++cb) bcur[cb] = bnxt[cb];
        }
    }

    // epilogue 2: e = exp(s); l += e; g += e*h (h re-read from global fp32,
    // L3-resident within block lifetime; also more accurate than bf16 copy).
    #pragma unroll
    for (int cb = 0; cb < 4; ++cb) {
        int col = wcol0 + cb * 16 + l16;
        float hv[16];
        #pragma unroll
        for (int rb = 0; rb < 4; ++rb)
            #pragma unroll
            for (int r = 0; r < 4; ++r)
                hv[rb * 4 + r] =
                    h[(size_t)(row0 + rb * 16 + quad * 4 + r) * DDIM + col];
        float lsum = 0.f, gsum = 0.f;
        #pragma unroll
        for (int rb = 0; rb < 4; ++rb)
            #pragma unroll
            for (int r = 0; r < 4; ++r) {
                float e = __expf(acc[rb][cb][r]);   // |s| small: no max-sub needed
                lsum += e;
                gsum += e * hv[rb * 4 + r];
            }
        lsum += __shfl_xor(lsum, 16);  lsum += __shfl_xor(lsum, 32);
        gsum += __shfl_xor(gsum, 16);  gsum += __shfl_xor(gsum, 32);
        if (quad == 0) {
            atomicAdd(&lbuf[b * DDIM + col], lsum);
            atomicAdd(&gbuf[b * DDIM + col], gsum);
        }
    }
}

// --- kernel 3: out[d] = sum_b g[b,d] / l[b,d] --------------------------------
__global__ void finish_kernel(const float* __restrict__ lbuf,
                              const float* __restrict__ gbuf,
                              float* __restrict__ out) {
    int d = blockIdx.x * blockDim.x + threadIdx.x;   // 0..511
    float s = 0.f;
    #pragma unroll
    for (int b = 0; b < BATCH; ++b)
        s += gbuf[b * DDIM + d] / lbuf[b * DDIM + d];
    out[d] = s;
}

extern "C" void kernel_launch(void* const* d_in, const int* in_sizes, int n_in,
                              void* d_out, int out_size, void* d_ws, size_t ws_size,
                              hipStream_t stream) {
    const float* h  = (const float*)d_in[0];
    const float* W1 = (const float*)d_in[1];
    const float* b1 = (const float*)d_in[2];
    const float* W2 = (const float*)d_in[3];
    float* out = (float*)d_out;

    char* ws = (char*)d_ws;
    short* W1b = (short*)ws;                              // 512 KB
    short* W2b = (short*)(ws + 512 * 1024);               // 512 KB
    float* lbuf = (float*)(ws + 1024 * 1024);             // 64 KB
    float* gbuf = (float*)(ws + 1024 * 1024 + 64 * 1024); // 64 KB

    prep_kernel<<<(DDIM * DDIM) / 256, 256, 0, stream>>>(W1, W2, W1b, W2b, lbuf, gbuf);
    main_kernel<<<(BATCH * TLEN) / BM, BLOCK, 0, stream>>>(h, W1b, b1, W2b, lbuf, gbuf);
    finish_kernel<<<2, 256, 0, stream>>>(lbuf, gbuf, out);
}

// Round 5
// 641.662 us; speedup vs baseline: 1.0180x; 1.0180x over previous
//
#include <hip/hip_runtime.h>
#include <hip/hip_bf16.h>
#include <math.h>

// Problem constants
#define BATCH 32
#define TLEN  4096
#define DDIM  512
#define BM    64      // rows (b*T+t) per block
#define BLOCK 1024    // 16 waves; wave w owns cols [w*32, w*32+32), all BM rows
// Why 1024/32-cols: acc regs per WAVE = BM*colsPerWave/64. At 64 cols/wave
// (rounds 2-4) acc=64 AGPR + ~100 arch = 164 unified -> only 2 waves/SIMD
// (occupancy 23%, latency-bound). At 32 cols/wave acc=32, total ~97 <= 128
// -> 4 waves/SIMD, same L2 B-traffic (block reads W once either way).

typedef __attribute__((ext_vector_type(8))) short bf16x8;  // MFMA A/B frag (4 VGPRs)
typedef __attribute__((ext_vector_type(4))) float f32x4;   // MFMA C/D frag
typedef __attribute__((ext_vector_type(4))) short s16x4;   // 8B LDS store

__device__ __forceinline__ short f32_to_bf16_rne(float f) {
    union { float f; unsigned int u; } v; v.f = f;
    unsigned int r = (v.u + 0x7FFFu + ((v.u >> 16) & 1u)) >> 16;
    return (short)r;
}
__device__ __forceinline__ float fast_tanh(float x) {
    x = fminf(fmaxf(x, -15.f), 15.f);
    float t = __expf(2.0f * x);
    return (t - 1.0f) / (t + 1.0f);
}

// XOR swizzle on 16B (8-short) granules. Measured 0 bank conflicts (r2-r4).
__device__ __forceinline__ int lds_idx(int r, int c) {
    int g = (c >> 3) ^ (r & 31);
    return r * DDIM + (g << 3) + (c & 7);
}

// --- kernel 1: W fp32 -> bf16, zero l/g accumulators -------------------------
__global__ void prep_kernel(const float* __restrict__ W1, const float* __restrict__ W2,
                            short* __restrict__ W1b, short* __restrict__ W2b,
                            float* __restrict__ lbuf, float* __restrict__ gbuf) {
    int i = blockIdx.x * blockDim.x + threadIdx.x;   // 0 .. 262143
    W1b[i] = f32_to_bf16_rne(W1[i]);
    W2b[i] = f32_to_bf16_rne(W2[i]);
    if (i < BATCH * DDIM) { lbuf[i] = 0.f; gbuf[i] = 0.f; }
}

// --- kernel 2: fused u=tanh(hW1^T+b1); s=uW2^T; accumulate l,g ---------------
// Single 64 KB LDS buffer (h tile, overwritten by u tile after GEMM1).
// Epilogue 2 re-reads h from global fp32 (cache-resident; r4 FETCH confirms).
__global__ __launch_bounds__(BLOCK, 4)   // 4 waves/EU = 16 waves/CU = 1 block;
                                         // unified reg cap 128 (need ~97)
void main_kernel(const float* __restrict__ h,
                 const short* __restrict__ W1b,
                 const float* __restrict__ b1,
                 const short* __restrict__ W2b,
                 float* __restrict__ lbuf, float* __restrict__ gbuf) {
    __shared__ short sh[BM * DDIM];   // 64 KB: h tile, then u tile (swizzled)

    const int tid  = threadIdx.x;
    const int row0 = blockIdx.x * BM;
    const int b    = row0 / TLEN;       // BM divides TLEN: no batch straddle

    // ---- stage 1: global fp32 h -> LDS bf16 (coalesced float4 loads) ----
    {
        const float4* hp = (const float4*)(h + (size_t)row0 * DDIM);
        #pragma unroll
        for (int i = 0; i < (BM * DDIM / 4) / BLOCK; ++i) {   // 8 iters
            int idx  = tid + i * BLOCK;          // float4 index
            float4 v = hp[idx];
            int flat = idx * 4;
            int r = flat >> 9;                   // /512
            int c = flat & (DDIM - 1);
            s16x4 p;
            p.x = f32_to_bf16_rne(v.x); p.y = f32_to_bf16_rne(v.y);
            p.z = f32_to_bf16_rne(v.z); p.w = f32_to_bf16_rne(v.w);
            *(s16x4*)&sh[lds_idx(r, c)] = p;
        }
    }
    __syncthreads();

    const int wave  = tid >> 6;
    const int lane  = tid & 63;
    const int quad  = lane >> 4;
    const int l16   = lane & 15;
    const int wcol0 = wave * 32;        // this wave's 32-col slice
    const int kq    = quad * 8;

    // ================= GEMM1: u = tanh(h @ W1^T + b1) =================
    f32x4 acc[4][2];                    // [rowblk][colblk] = 32 regs
    #pragma unroll
    for (int rb = 0; rb < 4; ++rb)
        #pragma unroll
        for (int cb = 0; cb < 2; ++cb) acc[rb][cb] = (f32x4){0.f, 0.f, 0.f, 0.f};

    {
        const short* Bb = W1b + (size_t)(wcol0 + l16) * DDIM + kq;
        bf16x8 bcur[2], bnxt[2];
        #pragma unroll
        for (int cb = 0; cb < 2; ++cb)
            bcur[cb] = *(const bf16x8*)(Bb + cb * 16 * DDIM);

        for (int k0 = 0; k0 < DDIM; k0 += 32) {
            bf16x8 af[4];
            #pragma unroll
            for (int rb = 0; rb < 4; ++rb)
                af[rb] = *(const bf16x8*)&sh[lds_idx(rb * 16 + l16, k0 + kq)];
            // prefetch next k-chunk of B (last iter overreads into adjacent ws
            // buffers -- allocated, unused)
            #pragma unroll
            for (int cb = 0; cb < 2; ++cb)
                bnxt[cb] = *(const bf16x8*)(Bb + cb * 16 * DDIM + k0 + 32);
            #pragma unroll
            for (int cb = 0; cb < 2; ++cb)
                #pragma unroll
                for (int rb = 0; rb < 4; ++rb)
                    acc[rb][cb] = __builtin_amdgcn_mfma_f32_16x16x32_bf16(
                        af[rb], bcur[cb], acc[rb][cb], 0, 0, 0);
            #pragma unroll
            for (int cb = 0; cb < 2; ++cb) bcur[cb] = bnxt[cb];
        }
    }

    __syncthreads();   // all waves done reading h tile before u overwrites it

    // epilogue 1: u = tanh(acc + bias) -> sh (overwrite h tile)
    #pragma unroll
    for (int cb = 0; cb < 2; ++cb) {
        int col  = wcol0 + cb * 16 + l16;
        float bias = b1[col];
        #pragma unroll
        for (int rb = 0; rb < 4; ++rb)
            #pragma unroll
            for (int r = 0; r < 4; ++r) {
                int row = rb * 16 + quad * 4 + r;   // C/D: col=lane&15, row=quad*4+reg
                sh[lds_idx(row, col)] =
                    f32_to_bf16_rne(fast_tanh(acc[rb][cb][r] + bias));
            }
    }
    __syncthreads();

    // ================= GEMM2: s = u @ W2^T; accumulate l,g =================
    #pragma unroll
    for (int rb = 0; rb < 4; ++rb)
        #pragma unroll
        for (int cb = 0; cb < 2; ++cb) acc[rb][cb] = (f32x4){0.f, 0.f, 0.f, 0.f};

    {
        const short* Bb = W2b + (size_t)(wcol0 + l16) * DDIM + kq;
        bf16x8 bcur[2], bnxt[2];
        #pragma unroll
        for (int cb = 0; cb < 2; ++cb)
            bcur[cb] = *(const bf16x8*)(Bb + cb * 16 * DDIM);

        for (int k0 = 0; k0 < DDIM; k0 += 32) {
            bf16x8 af[4];
            #pragma unroll
            for (int rb = 0; rb < 4; ++rb)
                af[rb] = *(const bf16x8*)&sh[lds_idx(rb * 16 + l16, k0 + kq)];
            #pragma unroll
            for (int cb = 0; cb < 2; ++cb)
                bnxt[cb] = *(const bf16x8*)(Bb + cb * 16 * DDIM + k0 + 32);
            #pragma unroll
            for (int cb = 0; cb < 2; ++cb)
                #pragma unroll
                for (int rb = 0; rb < 4; ++rb)
                    acc[rb][cb] = __builtin_amdgcn_mfma_f32_16x16x32_bf16(
                        af[rb], bcur[cb], acc[rb][cb], 0, 0, 0);
            #pragma unroll
            for (int cb = 0; cb < 2; ++cb) bcur[cb] = bnxt[cb];
        }
    }

    // epilogue 2: e = exp(s); l += e; g += e*h (h re-read from global fp32,
    // cache-resident within block lifetime; also more accurate than bf16 copy).
    #pragma unroll
    for (int cb = 0; cb < 2; ++cb) {
        int col = wcol0 + cb * 16 + l16;
        float hv[16];
        #pragma unroll
        for (int rb = 0; rb < 4; ++rb)
            #pragma unroll
            for (int r = 0; r < 4; ++r)
                hv[rb * 4 + r] =
                    h[(size_t)(row0 + rb * 16 + quad * 4 + r) * DDIM + col];
        float lsum = 0.f, gsum = 0.f;
        #pragma unroll
        for (int rb = 0; rb < 4; ++rb)
            #pragma unroll
            for (int r = 0; r < 4; ++r) {
                float e = __expf(acc[rb][cb][r]);   // |s| small: no max-sub needed
                lsum += e;
                gsum += e * hv[rb * 4 + r];
            }
        lsum += __shfl_xor(lsum, 16);  lsum += __shfl_xor(lsum, 32);
        gsum += __shfl_xor(gsum, 16);  gsum += __shfl_xor(gsum, 32);
        if (quad == 0) {
            atomicAdd(&lbuf[b * DDIM + col], lsum);
            atomicAdd(&gbuf[b * DDIM + col], gsum);
        }
    }
}

// --- kernel 3: out[d] = sum_b g[b,d] / l[b,d] --------------------------------
__global__ void finish_kernel(const float* __restrict__ lbuf,
                              const float* __restrict__ gbuf,
                              float* __restrict__ out) {
    int d = blockIdx.x * blockDim.x + threadIdx.x;   // 0..511
    float s = 0.f;
    #pragma unroll
    for (int b = 0; b < BATCH; ++b)
        s += gbuf[b * DDIM + d] / lbuf[b * DDIM + d];
    out[d] = s;
}

extern "C" void kernel_launch(void* const* d_in, const int* in_sizes, int n_in,
                              void* d_out, int out_size, void* d_ws, size_t ws_size,
                              hipStream_t stream) {
    const float* h  = (const float*)d_in[0];
    const float* W1 = (const float*)d_in[1];
    const float* b1 = (const float*)d_in[2];
    const float* W2 = (const float*)d_in[3];
    float* out = (float*)d_out;

    char* ws = (char*)d_ws;
    short* W1b = (short*)ws;                              // 512 KB
    short* W2b = (short*)(ws + 512 * 1024);               // 512 KB
    float* lbuf = (float*)(ws + 1024 * 1024);             // 64 KB
    float* gbuf = (float*)(ws + 1024 * 1024 + 64 * 1024); // 64 KB

    prep_kernel<<<(DDIM * DDIM) / 256, 256, 0, stream>>>(W1, W2, W1b, W2b, lbuf, gbuf);
    main_kernel<<<(BATCH * TLEN) / BM, BLOCK, 0, stream>>>(h, W1b, b1, W2b, lbuf, gbuf);
    finish_kernel<<<2, 256, 0, stream>>>(lbuf, gbuf, out);
}

// Round 6
// 641.656 us; speedup vs baseline: 1.0180x; 1.0000x over previous
//
#include <hip/hip_runtime.h>
#include <hip/hip_bf16.h>
#include <math.h>

// Problem constants
#define BATCH 32
#define TLEN  4096
#define DDIM  512
#define BM    64      // rows per block
#define BLOCK 512     // 8 waves. Wave w covers cols {w*32, w*32+256} in 2 passes.
// Why 2-pass/8-wave (r6): r2-r5 all ran 1 block/CU -> every __syncthreads
// drained the whole CU (MfmaUtil pinned at 14% = exact MFMA floor, 85% bubbles).
// 8-wave block with acc reuse across passes keeps regs ~<=112 and LDS 64 KB ->
// 2 blocks/CU co-resident; phases of the two blocks interleave.

typedef __attribute__((ext_vector_type(8))) short bf16x8;  // MFMA A/B frag
typedef __attribute__((ext_vector_type(4))) float f32x4;   // MFMA C/D frag
typedef __attribute__((ext_vector_type(4))) short s16x4;   // 8B LDS store

__device__ __forceinline__ short f32_to_bf16_rne(float f) {
    union { float f; unsigned int u; } v; v.f = f;
    unsigned int r = (v.u + 0x7FFFu + ((v.u >> 16) & 1u)) >> 16;
    return (short)r;
}
__device__ __forceinline__ float bf16_to_f32(short s) {
    union { unsigned int u; float f; } v;
    v.u = ((unsigned int)(unsigned short)s) << 16;
    return v.f;
}
__device__ __forceinline__ float fast_tanh(float x) {
    x = fminf(fmaxf(x, -15.f), 15.f);
    float t = __expf(2.0f * x);
    return (t - 1.0f) / (t + 1.0f);
}

// XOR swizzle on 16B (8-short) granules. Measured 0 bank conflicts (r2-r5).
__device__ __forceinline__ int lds_idx(int r, int c) {
    int g = (c >> 3) ^ (r & 31);
    return r * DDIM + (g << 3) + (c & 7);
}

// --- kernel 1: W fp32 -> bf16, zero l/g accumulators -------------------------
__global__ void prep_kernel(const float* __restrict__ W1, const float* __restrict__ W2,
                            short* __restrict__ W1b, short* __restrict__ W2b,
                            float* __restrict__ lbuf, float* __restrict__ gbuf) {
    int i = blockIdx.x * blockDim.x + threadIdx.x;   // 0 .. 262143
    W1b[i] = f32_to_bf16_rne(W1[i]);
    W2b[i] = f32_to_bf16_rne(W2[i]);
    if (i < BATCH * DDIM) { lbuf[i] = 0.f; gbuf[i] = 0.f; }
}

// --- kernel 2: fused u=tanh(hW1^T+b1); s=uW2^T; accumulate l,g ---------------
// Single 64 KB LDS buffer: h tile, overwritten by u tile after GEMM1 completes.
// launch_bounds stays (512,2): r3 showed forcing 4 waves/EU caps arch regs at 64
// and spills to scratch. Natural usage ~<=112 lets HW run 4 waves/EU anyway.
__global__ __launch_bounds__(BLOCK, 2)
void main_kernel(const float* __restrict__ h,
                 const short* __restrict__ W1b,
                 const float* __restrict__ b1,
                 const short* __restrict__ W2b,
                 float* __restrict__ lbuf, float* __restrict__ gbuf) {
    __shared__ short sh[BM * DDIM];   // 64 KB: h tile, then u tile (swizzled)

    const int tid  = threadIdx.x;
    const int row0 = blockIdx.x * BM;
    const int b    = row0 / TLEN;       // BM divides TLEN: no batch straddle

    // ---- stage 1: global fp32 h -> LDS bf16 (coalesced float4 loads) ----
    {
        const float4* hp = (const float4*)(h + (size_t)row0 * DDIM);
        #pragma unroll
        for (int i = 0; i < (BM * DDIM / 4) / BLOCK; ++i) {   // 16 iters
            int idx  = tid + i * BLOCK;          // float4 index
            float4 v = hp[idx];
            int flat = idx * 4;
            int r = flat >> 9;                   // /512
            int c = flat & (DDIM - 1);
            s16x4 p;
            p.x = f32_to_bf16_rne(v.x); p.y = f32_to_bf16_rne(v.y);
            p.z = f32_to_bf16_rne(v.z); p.w = f32_to_bf16_rne(v.w);
            *(s16x4*)&sh[lds_idx(r, c)] = p;
        }
    }
    __syncthreads();

    const int wave = tid >> 6;
    const int lane = tid & 63;
    const int quad = lane >> 4;
    const int l16  = lane & 15;
    const int kq   = quad * 8;

    // ================= GEMM1: u = tanh(h @ W1^T + b1), 2 col passes ==========
    unsigned int u0pk[16];              // pass-0 u, packed 2x bf16 (cb0 lo, cb1 hi)
    f32x4 acc[4][2];                    // [rowblk][colblk], reused across passes

    #pragma unroll
    for (int pass = 0; pass < 2; ++pass) {
        const int col0 = wave * 32 + pass * 256;
        #pragma unroll
        for (int rb = 0; rb < 4; ++rb)
            #pragma unroll
            for (int cb = 0; cb < 2; ++cb) acc[rb][cb] = (f32x4){0.f,0.f,0.f,0.f};

        const short* Bb = W1b + (size_t)(col0 + l16) * DDIM + kq;
        bf16x8 bcur[2], bnxt[2];
        #pragma unroll
        for (int cb = 0; cb < 2; ++cb)
            bcur[cb] = *(const bf16x8*)(Bb + cb * 16 * DDIM);

        for (int k0 = 0; k0 < DDIM; k0 += 32) {
            bf16x8 af[4];
            #pragma unroll
            for (int rb = 0; rb < 4; ++rb)
                af[rb] = *(const bf16x8*)&sh[lds_idx(rb * 16 + l16, k0 + kq)];
            // prefetch next k-chunk (last iter overreads into adjacent ws: ok)
            #pragma unroll
            for (int cb = 0; cb < 2; ++cb)
                bnxt[cb] = *(const bf16x8*)(Bb + cb * 16 * DDIM + k0 + 32);
            #pragma unroll
            for (int cb = 0; cb < 2; ++cb)
                #pragma unroll
                for (int rb = 0; rb < 4; ++rb)
                    acc[rb][cb] = __builtin_amdgcn_mfma_f32_16x16x32_bf16(
                        af[rb], bcur[cb], acc[rb][cb], 0, 0, 0);
            #pragma unroll
            for (int cb = 0; cb < 2; ++cb) bcur[cb] = bnxt[cb];
        }

        // tanh + bias; pass 0 -> packed regs, pass 1 stays in acc (f32)
        #pragma unroll
        for (int cb = 0; cb < 2; ++cb) {
            float bias = b1[col0 + cb * 16 + l16];
            #pragma unroll
            for (int rb = 0; rb < 4; ++rb)
                #pragma unroll
                for (int r = 0; r < 4; ++r)
                    acc[rb][cb][r] = fast_tanh(acc[rb][cb][r] + bias);
        }
        if (pass == 0) {
            #pragma unroll
            for (int rb = 0; rb < 4; ++rb)
                #pragma unroll
                for (int r = 0; r < 4; ++r)
                    u0pk[rb * 4 + r] =
                        ((unsigned int)(unsigned short)f32_to_bf16_rne(acc[rb][0][r])) |
                        (((unsigned int)(unsigned short)f32_to_bf16_rne(acc[rb][1][r])) << 16);
        }
    }

    __syncthreads();   // all waves done reading h tile; safe to overwrite with u

    // write u (both passes) into sh
    #pragma unroll
    for (int cb = 0; cb < 2; ++cb) {
        int c0 = wave * 32 + cb * 16 + l16;        // pass 0 col
        int c1 = c0 + 256;                         // pass 1 col
        #pragma unroll
        for (int rb = 0; rb < 4; ++rb)
            #pragma unroll
            for (int r = 0; r < 4; ++r) {
                int row = rb * 16 + quad * 4 + r;  // C/D: col=lane&15, row=quad*4+reg
                sh[lds_idx(row, c0)] = (short)(u0pk[rb * 4 + r] >> (cb * 16));
                sh[lds_idx(row, c1)] = f32_to_bf16_rne(acc[rb][cb][r]);
            }
    }
    __syncthreads();

    // ================= GEMM2: s = u @ W2^T; accumulate l,g; 2 col passes =====
    #pragma unroll
    for (int pass = 0; pass < 2; ++pass) {
        const int col0 = wave * 32 + pass * 256;
        #pragma unroll
        for (int rb = 0; rb < 4; ++rb)
            #pragma unroll
            for (int cb = 0; cb < 2; ++cb) acc[rb][cb] = (f32x4){0.f,0.f,0.f,0.f};

        const short* Bb = W2b + (size_t)(col0 + l16) * DDIM + kq;
        bf16x8 bcur[2], bnxt[2];
        #pragma unroll
        for (int cb = 0; cb < 2; ++cb)
            bcur[cb] = *(const bf16x8*)(Bb + cb * 16 * DDIM);

        for (int k0 = 0; k0 < DDIM; k0 += 32) {
            bf16x8 af[4];
            #pragma unroll
            for (int rb = 0; rb < 4; ++rb)
                af[rb] = *(const bf16x8*)&sh[lds_idx(rb * 16 + l16, k0 + kq)];
            #pragma unroll
            for (int cb = 0; cb < 2; ++cb)
                bnxt[cb] = *(const bf16x8*)(Bb + cb * 16 * DDIM + k0 + 32);
            #pragma unroll
            for (int cb = 0; cb < 2; ++cb)
                #pragma unroll
                for (int rb = 0; rb < 4; ++rb)
                    acc[rb][cb] = __builtin_amdgcn_mfma_f32_16x16x32_bf16(
                        af[rb], bcur[cb], acc[rb][cb], 0, 0, 0);
            #pragma unroll
            for (int cb = 0; cb < 2; ++cb) bcur[cb] = bnxt[cb];
        }

        // epilogue: e = exp(s); l += e; g += e*h (h re-read from global fp32)
        #pragma unroll
        for (int cb = 0; cb < 2; ++cb) {
            int col = col0 + cb * 16 + l16;
            float hv[16];
            #pragma unroll
            for (int rb = 0; rb < 4; ++rb)
                #pragma unroll
                for (int r = 0; r < 4; ++r)
                    hv[rb * 4 + r] =
                        h[(size_t)(row0 + rb * 16 + quad * 4 + r) * DDIM + col];
            float lsum = 0.f, gsum = 0.f;
            #pragma unroll
            for (int rb = 0; rb < 4; ++rb)
                #pragma unroll
                for (int r = 0; r < 4; ++r) {
                    float e = __expf(acc[rb][cb][r]);  // |s| small: no max-sub
                    lsum += e;
                    gsum += e * hv[rb * 4 + r];
                }
            lsum += __shfl_xor(lsum, 16);  lsum += __shfl_xor(lsum, 32);
            gsum += __shfl_xor(gsum, 16);  gsum += __shfl_xor(gsum, 32);
            if (quad == 0) {
                atomicAdd(&lbuf[b * DDIM + col], lsum);
                atomicAdd(&gbuf[b * DDIM + col], gsum);
            }
        }
    }
}

// --- kernel 3: out[d] = sum_b g[b,d] / l[b,d] --------------------------------
__global__ void finish_kernel(const float* __restrict__ lbuf,
                              const float* __restrict__ gbuf,
                              float* __restrict__ out) {
    int d = blockIdx.x * blockDim.x + threadIdx.x;   // 0..511
    float s = 0.f;
    #pragma unroll
    for (int b = 0; b < BATCH; ++b)
        s += gbuf[b * DDIM + d] / lbuf[b * DDIM + d];
    out[d] = s;
}

extern "C" void kernel_launch(void* const* d_in, const int* in_sizes, int n_in,
                              void* d_out, int out_size, void* d_ws, size_t ws_size,
                              hipStream_t stream) {
    const float* h  = (const float*)d_in[0];
    const float* W1 = (const float*)d_in[1];
    const float* b1 = (const float*)d_in[2];
    const float* W2 = (const float*)d_in[3];
    float* out = (float*)d_out;

    char* ws = (char*)d_ws;
    short* W1b = (short*)ws;                              // 512 KB
    short* W2b = (short*)(ws + 512 * 1024);               // 512 KB
    float* lbuf = (float*)(ws + 1024 * 1024);             // 64 KB
    float* gbuf = (float*)(ws + 1024 * 1024 + 64 * 1024); // 64 KB

    prep_kernel<<<(DDIM * DDIM) / 256, 256, 0, stream>>>(W1, W2, W1b, W2b, lbuf, gbuf);
    main_kernel<<<(BATCH * TLEN) / BM, BLOCK, 0, stream>>>(h, W1b, b1, W2b, lbuf, gbuf);
    finish_kernel<<<2, 256, 0, stream>>>(lbuf, gbuf, out);
}